// Round 1
// baseline (6670.794 us; speedup 1.0000x reference)
//
#include <hip/hip_runtime.h>
#include <cstdint>
#include <cstddef>

#define EMB   256
#define D0    66
#define NA    16384
#define NOBJ  32768
#define E1CNT 131072
#define E2CNT 262144
#define NDEC  1056
#define DEC_OFF ((size_t)NA * NDEC)   // 17301504

#define BM 64

// ---------------------------------------------------------------------------
// helpers
// ---------------------------------------------------------------------------
__device__ __forceinline__ void load_w16(const float* __restrict__ p, float wv[16]) {
  float4 q0 = *(const float4*)(p + 0);
  float4 q1 = *(const float4*)(p + 4);
  float4 q2 = *(const float4*)(p + 8);
  float4 q3 = *(const float4*)(p + 12);
  wv[0] = q0.x; wv[1] = q0.y; wv[2]  = q0.z; wv[3]  = q0.w;
  wv[4] = q1.x; wv[5] = q1.y; wv[6]  = q1.z; wv[7]  = q1.w;
  wv[8] = q2.x; wv[9] = q2.y; wv[10] = q2.z; wv[11] = q2.w;
  wv[12] = q3.x; wv[13] = q3.y; wv[14] = q3.z; wv[15] = q3.w;
}

__device__ __forceinline__ void fma_tile(float acc[4][16], const float av[4], const float wv[16]) {
#pragma unroll
  for (int i = 0; i < 4; ++i)
#pragma unroll
    for (int j = 0; j < 16; ++j)
      acc[i][j] = fmaf(av[i], wv[j], acc[i][j]);
}

// ---------------------------------------------------------------------------
// K1: h1 = relu(msg @ W_enc1 + b1), msg gathered per obs-edge
// grid.x = ce/64, block = 256
// ---------------------------------------------------------------------------
__global__ __launch_bounds__(256) void k_enc1(
    const float* __restrict__ obj_x, const float* __restrict__ obj_pos,
    const float* __restrict__ agent_pos,
    const int* __restrict__ agent_idx, const int* __restrict__ obj_idx,
    const float* __restrict__ W1, const float* __restrict__ b1,
    float* __restrict__ h1)
{
  __shared__ float A[BM][68];
  const int tid = threadIdx.x;
  const int m0  = blockIdx.x * BM;
  {
    const int r = tid >> 2, part = tid & 3;
    const int e = m0 + r;
    const int o = obj_idx[e];
    const float4* s4 = (const float4*)(obj_x + (size_t)o * 64 + part * 16);
    float4 v0 = s4[0], v1 = s4[1], v2 = s4[2], v3 = s4[3];
    float4* d4 = (float4*)&A[r][part * 16];
    d4[0] = v0; d4[1] = v1; d4[2] = v2; d4[3] = v3;
    if (part == 0) {
      const int a = agent_idx[e];
      A[r][64] = obj_pos[(size_t)o * 2 + 0] - agent_pos[(size_t)a * 2 + 0];
      A[r][65] = obj_pos[(size_t)o * 2 + 1] - agent_pos[(size_t)a * 2 + 1];
    }
  }
  __syncthreads();

  const int tx = tid & 15, ty = tid >> 4;
  float acc[4][16] = {};
  const float* wbase = W1 + tx * 16;
  for (int k = 0; k < 66; ++k) {
    float wv[16];
    load_w16(wbase + (size_t)k * 256, wv);
    float av[4];
#pragma unroll
    for (int i = 0; i < 4; ++i) av[i] = A[ty * 4 + i][k];
    fma_tile(acc, av, wv);
  }

  float bv[16];
  load_w16(b1 + tx * 16, bv);
#pragma unroll
  for (int i = 0; i < 4; ++i) {
    float* out = h1 + (size_t)(m0 + ty * 4 + i) * 256 + tx * 16;
#pragma unroll
    for (int j = 0; j < 16; j += 4) {
      float4 o4;
      o4.x = fmaxf(acc[i][j + 0] + bv[j + 0], 0.f);
      o4.y = fmaxf(acc[i][j + 1] + bv[j + 1], 0.f);
      o4.z = fmaxf(acc[i][j + 2] + bv[j + 2], 0.f);
      o4.w = fmaxf(acc[i][j + 3] + bv[j + 3], 0.f);
      *(float4*)(out + j) = o4;
    }
  }
}

// ---------------------------------------------------------------------------
// K2: h = h1 @ W_enc2 + b2 ; atomicAdd rows into enc[agent_idx[row]]
// ---------------------------------------------------------------------------
__global__ __launch_bounds__(256) void k_enc2(
    const float* __restrict__ h1,
    const float* __restrict__ W2, const float* __restrict__ b2,
    const int* __restrict__ agent_idx,
    float* __restrict__ enc)
{
  __shared__ float A[BM][68];
  const int tid = threadIdx.x;
  const int m0  = blockIdx.x * BM;
  const int tx = tid & 15, ty = tid >> 4;
  const int r = tid >> 2, part = tid & 3;
  float acc[4][16] = {};

  for (int kc = 0; kc < 4; ++kc) {
    __syncthreads();
    const float4* s4 = (const float4*)(h1 + (size_t)(m0 + r) * 256 + kc * 64 + part * 16);
    float4 v0 = s4[0], v1 = s4[1], v2 = s4[2], v3 = s4[3];
    float4* d4 = (float4*)&A[r][part * 16];
    d4[0] = v0; d4[1] = v1; d4[2] = v2; d4[3] = v3;
    __syncthreads();
    const float* wbase = W2 + (size_t)(kc * 64) * 256 + tx * 16;
    for (int k = 0; k < 64; ++k) {
      float wv[16];
      load_w16(wbase + (size_t)k * 256, wv);
      float av[4];
#pragma unroll
      for (int i = 0; i < 4; ++i) av[i] = A[ty * 4 + i][k];
      fma_tile(acc, av, wv);
    }
  }

  float bv[16];
  load_w16(b2 + tx * 16, bv);
#pragma unroll
  for (int i = 0; i < 4; ++i) {
    const int row = m0 + ty * 4 + i;
    const int a = agent_idx[row];
    float* dst = enc + (size_t)a * 256 + tx * 16;
#pragma unroll
    for (int j = 0; j < 16; ++j)
      atomicAdd(dst + j, acc[i][j] + bv[j]);
  }
}

// ---------------------------------------------------------------------------
// K3: m = relu(concat(enc[src], rel) @ W_msg + bm) ; atomicAdd into agg[dst]
// ---------------------------------------------------------------------------
__global__ __launch_bounds__(256) void k_msg(
    const float* __restrict__ enc,
    const float* __restrict__ agent_pos,
    const int* __restrict__ src, const int* __restrict__ dst_idx,
    const float* __restrict__ Wm, const float* __restrict__ bm,
    float* __restrict__ agg)
{
  __shared__ float A[BM][68];
  const int tid = threadIdx.x;
  const int m0  = blockIdx.x * BM;
  const int tx = tid & 15, ty = tid >> 4;
  const int r = tid >> 2, part = tid & 3;
  const int e = m0 + r;
  const int s = src[e];
  float acc[4][16] = {};

  for (int kc = 0; kc < 4; ++kc) {
    __syncthreads();
    const float4* s4 = (const float4*)(enc + (size_t)s * 256 + kc * 64 + part * 16);
    float4 v0 = s4[0], v1 = s4[1], v2 = s4[2], v3 = s4[3];
    float4* d4 = (float4*)&A[r][part * 16];
    d4[0] = v0; d4[1] = v1; d4[2] = v2; d4[3] = v3;
    __syncthreads();
    const float* wbase = Wm + (size_t)(kc * 64) * 256 + tx * 16;
    for (int k = 0; k < 64; ++k) {
      float wv[16];
      load_w16(wbase + (size_t)k * 256, wv);
      float av[4];
#pragma unroll
      for (int i = 0; i < 4; ++i) av[i] = A[ty * 4 + i][k];
      fma_tile(acc, av, wv);
    }
  }

  // rel columns: k = 256, 257
  __syncthreads();
  if (part == 0) {
    const int d = dst_idx[e];
    A[r][0] = agent_pos[(size_t)s * 2 + 0] - agent_pos[(size_t)d * 2 + 0];
    A[r][1] = agent_pos[(size_t)s * 2 + 1] - agent_pos[(size_t)d * 2 + 1];
  }
  __syncthreads();
  for (int k = 0; k < 2; ++k) {
    float wv[16];
    load_w16(Wm + (size_t)(256 + k) * 256 + tx * 16, wv);
    float av[4];
#pragma unroll
    for (int i = 0; i < 4; ++i) av[i] = A[ty * 4 + i][k];
    fma_tile(acc, av, wv);
  }

  float bv[16];
  load_w16(bm + tx * 16, bv);
#pragma unroll
  for (int i = 0; i < 4; ++i) {
    const int row = m0 + ty * 4 + i;
    const int d = dst_idx[row];
    float* dstp = agg + (size_t)d * 256 + tx * 16;
#pragma unroll
    for (int j = 0; j < 16; ++j)
      atomicAdd(dstp + j, fmaxf(acc[i][j] + bv[j], 0.f));
  }
}

// ---------------------------------------------------------------------------
// K4: x = relu(concat(enc, agg) @ W_upd + bu)
// ---------------------------------------------------------------------------
__global__ __launch_bounds__(256) void k_upd(
    const float* __restrict__ enc, const float* __restrict__ agg,
    const float* __restrict__ Wu, const float* __restrict__ bu,
    float* __restrict__ x)
{
  __shared__ float A[BM][68];
  const int tid = threadIdx.x;
  const int m0  = blockIdx.x * BM;
  const int tx = tid & 15, ty = tid >> 4;
  const int r = tid >> 2, part = tid & 3;
  float acc[4][16] = {};

  for (int kc = 0; kc < 8; ++kc) {
    const float* base = (kc < 4) ? enc : agg;
    const int ko = (kc & 3) * 64;
    __syncthreads();
    const float4* s4 = (const float4*)(base + (size_t)(m0 + r) * 256 + ko + part * 16);
    float4 v0 = s4[0], v1 = s4[1], v2 = s4[2], v3 = s4[3];
    float4* d4 = (float4*)&A[r][part * 16];
    d4[0] = v0; d4[1] = v1; d4[2] = v2; d4[3] = v3;
    __syncthreads();
    const float* wbase = Wu + (size_t)(kc * 64) * 256 + tx * 16;
    for (int k = 0; k < 64; ++k) {
      float wv[16];
      load_w16(wbase + (size_t)k * 256, wv);
      float av[4];
#pragma unroll
      for (int i = 0; i < 4; ++i) av[i] = A[ty * 4 + i][k];
      fma_tile(acc, av, wv);
    }
  }

  float bv[16];
  load_w16(bu + tx * 16, bv);
#pragma unroll
  for (int i = 0; i < 4; ++i) {
    float* out = x + (size_t)(m0 + ty * 4 + i) * 256 + tx * 16;
#pragma unroll
    for (int j = 0; j < 16; j += 4) {
      float4 o4;
      o4.x = fmaxf(acc[i][j + 0] + bv[j + 0], 0.f);
      o4.y = fmaxf(acc[i][j + 1] + bv[j + 1], 0.f);
      o4.z = fmaxf(acc[i][j + 2] + bv[j + 2], 0.f);
      o4.w = fmaxf(acc[i][j + 3] + bv[j + 3], 0.f);
      *(float4*)(out + j) = o4;
    }
  }
}

// ---------------------------------------------------------------------------
// K5: decoded = x @ W_dec + bd  -> out[0 : NA*1056)
// grid = (NA/64, 5); col tile 256, tail 32 handled by clamp+guard
// ---------------------------------------------------------------------------
__global__ __launch_bounds__(256) void k_dec(
    const float* __restrict__ x,
    const float* __restrict__ Wd, const float* __restrict__ bd,
    float* __restrict__ out)
{
  __shared__ float A[BM][68];
  const int tid = threadIdx.x;
  const int m0  = blockIdx.x * BM;
  const int n0  = blockIdx.y * 256;
  const int tx = tid & 15, ty = tid >> 4;
  const int r = tid >> 2, part = tid & 3;

  int c0 = n0 + tx * 16;
  const bool active = (c0 < NDEC);
  if (c0 > NDEC - 16) c0 = NDEC - 16;

  float acc[4][16] = {};
  for (int kc = 0; kc < 4; ++kc) {
    __syncthreads();
    const float4* s4 = (const float4*)(x + (size_t)(m0 + r) * 256 + kc * 64 + part * 16);
    float4 v0 = s4[0], v1 = s4[1], v2 = s4[2], v3 = s4[3];
    float4* d4 = (float4*)&A[r][part * 16];
    d4[0] = v0; d4[1] = v1; d4[2] = v2; d4[3] = v3;
    __syncthreads();
    const float* wbase = Wd + (size_t)(kc * 64) * NDEC + c0;
    for (int k = 0; k < 64; ++k) {
      float wv[16];
      load_w16(wbase + (size_t)k * NDEC, wv);
      float av[4];
#pragma unroll
      for (int i = 0; i < 4; ++i) av[i] = A[ty * 4 + i][k];
      fma_tile(acc, av, wv);
    }
  }

  if (active) {
    float bv[16];
    load_w16(bd + c0, bv);
#pragma unroll
    for (int i = 0; i < 4; ++i) {
      float* o = out + (size_t)(m0 + ty * 4 + i) * NDEC + c0;
#pragma unroll
      for (int j = 0; j < 16; j += 4) {
        float4 o4;
        o4.x = acc[i][j + 0] + bv[j + 0];
        o4.y = acc[i][j + 1] + bv[j + 1];
        o4.z = acc[i][j + 2] + bv[j + 2];
        o4.w = acc[i][j + 3] + bv[j + 3];
        *(float4*)(o + j) = o4;
      }
    }
  }
}

// ---------------------------------------------------------------------------
// K6: batch[i] = i >> 4 (written as float; tuple out buffer is float32)
// ---------------------------------------------------------------------------
__global__ __launch_bounds__(256) void k_batch(float* __restrict__ out)
{
  const int i = blockIdx.x * 256 + threadIdx.x;
  out[DEC_OFF + (size_t)i] = (float)(i >> 4);
}

// ---------------------------------------------------------------------------
extern "C" void kernel_launch(void* const* d_in, const int* in_sizes, int n_in,
                              void* d_out, int out_size, void* d_ws, size_t ws_size,
                              hipStream_t stream) {
  const float* obj_x     = (const float*)d_in[0];
  const float* obj_pos   = (const float*)d_in[1];
  const float* agent_pos = (const float*)d_in[2];
  const int*   oae       = (const int*)d_in[3];   // [2][E1]: row0 agent, row1 obj
  const int*   ae        = (const int*)d_in[4];   // [2][E2]: row0 src, row1 dst
  const float* W1 = (const float*)d_in[5];
  const float* b1 = (const float*)d_in[6];
  const float* W2 = (const float*)d_in[7];
  const float* b2 = (const float*)d_in[8];
  const float* Wm = (const float*)d_in[9];
  const float* bm = (const float*)d_in[10];
  const float* Wu = (const float*)d_in[11];
  const float* bu = (const float*)d_in[12];
  const float* Wd = (const float*)d_in[13];
  const float* bd = (const float*)d_in[14];
  float* out = (float*)d_out;

  // workspace layout
  float* enc = (float*)d_ws;                         // NA*256
  float* agg = enc + (size_t)NA * 256;               // NA*256
  float* xb  = agg + (size_t)NA * 256;               // NA*256
  float* h1  = xb  + (size_t)NA * 256;               // chunked E1 rows * 256

  size_t fixed_floats = (size_t)3 * NA * 256;
  size_t h1_cap = (ws_size / 4 > fixed_floats) ? (ws_size / 4 - fixed_floats) : 0;
  long long chunk_ll = (long long)((h1_cap / 256) & ~(size_t)63);
  int chunk = (chunk_ll > E1CNT) ? E1CNT : (int)chunk_ll;
  if (chunk < 64) chunk = 64;  // below this ws is unusable anyway

  hipMemsetAsync(enc, 0, (size_t)NA * 256 * sizeof(float), stream);
  hipMemsetAsync(agg, 0, (size_t)NA * 256 * sizeof(float), stream);

  const int* agent_idx = oae;
  const int* obj_idx   = oae + E1CNT;
  for (int done = 0; done < E1CNT; done += chunk) {
    int ce = (E1CNT - done < chunk) ? (E1CNT - done) : chunk;
    k_enc1<<<ce / 64, 256, 0, stream>>>(obj_x, obj_pos, agent_pos,
                                        agent_idx + done, obj_idx + done, W1, b1, h1);
    k_enc2<<<ce / 64, 256, 0, stream>>>(h1, W2, b2, agent_idx + done, enc);
  }

  const int* src = ae;
  const int* dst = ae + E2CNT;
  k_msg<<<E2CNT / 64, 256, 0, stream>>>(enc, agent_pos, src, dst, Wm, bm, agg);
  k_upd<<<NA / 64, 256, 0, stream>>>(enc, agg, Wu, bu, xb);
  k_dec<<<dim3(NA / 64, 5), 256, 0, stream>>>(xb, Wd, bd, out);
  k_batch<<<(NA * 16) / 256, 256, 0, stream>>>(out);
}

// Round 2
// 914.712 us; speedup vs baseline: 7.2928x; 7.2928x over previous
//
#include <hip/hip_runtime.h>
#include <cstdint>
#include <cstddef>

#define EMB   256
#define NA    16384
#define NOBJ  32768
#define E1CNT 131072
#define E2CNT 262144
#define NDEC  1056
#define DEC_OFF ((size_t)NA * NDEC)

#define BM 64

// ---------------------------------------------------------------------------
// helpers
// ---------------------------------------------------------------------------
__device__ __forceinline__ void load_w16(const float* __restrict__ p, float wv[16]) {
  float4 q0 = *(const float4*)(p + 0);
  float4 q1 = *(const float4*)(p + 4);
  float4 q2 = *(const float4*)(p + 8);
  float4 q3 = *(const float4*)(p + 12);
  wv[0] = q0.x; wv[1] = q0.y; wv[2]  = q0.z; wv[3]  = q0.w;
  wv[4] = q1.x; wv[5] = q1.y; wv[6]  = q1.z; wv[7]  = q1.w;
  wv[8] = q2.x; wv[9] = q2.y; wv[10] = q2.z; wv[11] = q2.w;
  wv[12] = q3.x; wv[13] = q3.y; wv[14] = q3.z; wv[15] = q3.w;
}

__device__ __forceinline__ void fma_tile(float acc[4][16], const float av[4], const float wv[16]) {
#pragma unroll
  for (int i = 0; i < 4; ++i)
#pragma unroll
    for (int j = 0; j < 16; ++j)
      acc[i][j] = fmaf(av[i], wv[j], acc[i][j]);
}

// ---------------------------------------------------------------------------
// CSR build: count / scan / fill
// ---------------------------------------------------------------------------
__global__ __launch_bounds__(256) void k_count(const int* __restrict__ key, int n,
                                               int* __restrict__ cnt) {
  int e = blockIdx.x * 256 + threadIdx.x;
  if (e < n) atomicAdd(&cnt[key[e]], 1);
}

// one block per array; cnt is overwritten with row starts (cursor); rp gets row_ptr
__global__ __launch_bounds__(256) void k_scan(int* c1, int* r1, int* c2, int* r2) {
  int* cnt = (blockIdx.x == 0) ? c1 : c2;
  int* rp  = (blockIdx.x == 0) ? r1 : r2;
  const int n = NA;          // 16384, 64 per thread
  __shared__ int partial[256];
  const int tid = threadIdx.x;
  const int base = tid * 64;
  int local[64];
  int s = 0;
#pragma unroll
  for (int i = 0; i < 64; ++i) { local[i] = s; s += cnt[base + i]; }
  partial[tid] = s;
  __syncthreads();
  for (int off = 1; off < 256; off <<= 1) {
    int v = (tid >= off) ? partial[tid - off] : 0;
    __syncthreads();
    partial[tid] += v;
    __syncthreads();
  }
  const int offset = (tid == 0) ? 0 : partial[tid - 1];
#pragma unroll
  for (int i = 0; i < 64; ++i) {
    int v = offset + local[i];
    rp[base + i]  = v;
    cnt[base + i] = v;   // cursor for fill
  }
  if (tid == 255) rp[n] = partial[255];
}

__global__ __launch_bounds__(256) void k_fill(const int* __restrict__ key,
                                              const int* __restrict__ val, int n,
                                              int* __restrict__ cursor,
                                              int* __restrict__ out) {
  int e = blockIdx.x * 256 + threadIdx.x;
  if (e < n) {
    int p = atomicAdd(&cursor[key[e]], 1);
    out[p] = val[e];
  }
}

// ---------------------------------------------------------------------------
// K-zobj: zobj[o] = [obj_x[o], obj_pos[o]] @ W1 + b1   (no relu)
// ---------------------------------------------------------------------------
__global__ __launch_bounds__(256) void k_zobj(
    const float* __restrict__ obj_x, const float* __restrict__ obj_pos,
    const float* __restrict__ W1, const float* __restrict__ b1,
    float* __restrict__ zobj)
{
  __shared__ float A[BM][68];
  const int tid = threadIdx.x;
  const int m0  = blockIdx.x * BM;
  {
    const int r = tid >> 2, part = tid & 3;
    const int o = m0 + r;
    const float4* s4 = (const float4*)(obj_x + (size_t)o * 64 + part * 16);
    float4 v0 = s4[0], v1 = s4[1], v2 = s4[2], v3 = s4[3];
    float4* d4 = (float4*)&A[r][part * 16];
    d4[0] = v0; d4[1] = v1; d4[2] = v2; d4[3] = v3;
    if (part == 0) {
      A[r][64] = obj_pos[(size_t)o * 2 + 0];
      A[r][65] = obj_pos[(size_t)o * 2 + 1];
    }
  }
  __syncthreads();

  const int tx = tid & 15, ty = tid >> 4;
  float acc[4][16] = {};
  const float* wbase = W1 + tx * 16;
  for (int k = 0; k < 66; ++k) {
    float wv[16];
    load_w16(wbase + (size_t)k * 256, wv);
    float av[4];
#pragma unroll
    for (int i = 0; i < 4; ++i) av[i] = A[ty * 4 + i][k];
    fma_tile(acc, av, wv);
  }

  float bv[16];
  load_w16(b1 + tx * 16, bv);
#pragma unroll
  for (int i = 0; i < 4; ++i) {
    float* out = zobj + (size_t)(m0 + ty * 4 + i) * 256 + tx * 16;
#pragma unroll
    for (int j = 0; j < 16; j += 4) {
      float4 o4;
      o4.x = acc[i][j + 0] + bv[j + 0];
      o4.y = acc[i][j + 1] + bv[j + 1];
      o4.z = acc[i][j + 2] + bv[j + 2];
      o4.w = acc[i][j + 3] + bv[j + 3];
      *(float4*)(out + j) = o4;
    }
  }
}

// ---------------------------------------------------------------------------
// K-reduce1: s1[a] = sum_{e in CSR(a)} relu(zobj[obj_e] - agent_pos[a] @ W1p)
// one wave per agent; lane owns 4 contiguous cols
// ---------------------------------------------------------------------------
__global__ __launch_bounds__(256) void k_reduce1(
    const float* __restrict__ zobj, const float* __restrict__ agent_pos,
    const int* __restrict__ rp, const int* __restrict__ sorted_obj,
    const float* __restrict__ W1, float* __restrict__ s1)
{
  const int a    = blockIdx.x * 4 + (threadIdx.x >> 6);
  const int lane = threadIdx.x & 63;
  const float ax = agent_pos[(size_t)a * 2 + 0];
  const float ay = agent_pos[(size_t)a * 2 + 1];
  const float4 w0 = *(const float4*)(W1 + (size_t)64 * 256 + lane * 4);
  const float4 w1 = *(const float4*)(W1 + (size_t)65 * 256 + lane * 4);
  float4 tsh;
  tsh.x = ax * w0.x + ay * w1.x;
  tsh.y = ax * w0.y + ay * w1.y;
  tsh.z = ax * w0.z + ay * w1.z;
  tsh.w = ax * w0.w + ay * w1.w;
  float4 acc = {0.f, 0.f, 0.f, 0.f};
  const int e0 = rp[a], e1 = rp[a + 1];
  for (int i = e0; i < e1; ++i) {
    const int o = sorted_obj[i];
    float4 z = *(const float4*)(zobj + (size_t)o * 256 + lane * 4);
    acc.x += fmaxf(z.x - tsh.x, 0.f);
    acc.y += fmaxf(z.y - tsh.y, 0.f);
    acc.z += fmaxf(z.z - tsh.z, 0.f);
    acc.w += fmaxf(z.w - tsh.w, 0.f);
  }
  *(float4*)(s1 + (size_t)a * 256 + lane * 4) = acc;
}

// ---------------------------------------------------------------------------
// K-gemm-enc: enc = s1 @ W2 + deg * b2   (no relu; deg from rp1)
// ---------------------------------------------------------------------------
__global__ __launch_bounds__(256) void k_gemm_enc(
    const float* __restrict__ s1,
    const float* __restrict__ W2, const float* __restrict__ b2,
    const int* __restrict__ rp,
    float* __restrict__ enc)
{
  __shared__ float A[BM][68];
  const int tid = threadIdx.x;
  const int m0  = blockIdx.x * BM;
  const int tx = tid & 15, ty = tid >> 4;
  const int r = tid >> 2, part = tid & 3;
  float acc[4][16] = {};

  for (int kc = 0; kc < 4; ++kc) {
    __syncthreads();
    const float4* s4 = (const float4*)(s1 + (size_t)(m0 + r) * 256 + kc * 64 + part * 16);
    float4 v0 = s4[0], v1 = s4[1], v2 = s4[2], v3 = s4[3];
    float4* d4 = (float4*)&A[r][part * 16];
    d4[0] = v0; d4[1] = v1; d4[2] = v2; d4[3] = v3;
    __syncthreads();
    const float* wbase = W2 + (size_t)(kc * 64) * 256 + tx * 16;
    for (int k = 0; k < 64; ++k) {
      float wv[16];
      load_w16(wbase + (size_t)k * 256, wv);
      float av[4];
#pragma unroll
      for (int i = 0; i < 4; ++i) av[i] = A[ty * 4 + i][k];
      fma_tile(acc, av, wv);
    }
  }

  float bv[16];
  load_w16(b2 + tx * 16, bv);
#pragma unroll
  for (int i = 0; i < 4; ++i) {
    const int row = m0 + ty * 4 + i;
    const float deg = (float)(rp[row + 1] - rp[row]);
    float* out = enc + (size_t)row * 256 + tx * 16;
#pragma unroll
    for (int j = 0; j < 16; j += 4) {
      float4 o4;
      o4.x = acc[i][j + 0] + deg * bv[j + 0];
      o4.y = acc[i][j + 1] + deg * bv[j + 1];
      o4.z = acc[i][j + 2] + deg * bv[j + 2];
      o4.w = acc[i][j + 3] + deg * bv[j + 3];
      *(float4*)(out + j) = o4;
    }
  }
}

// ---------------------------------------------------------------------------
// K-gemm-y: y = enc @ Wm[0:256] + bm   (no relu)
// ---------------------------------------------------------------------------
__global__ __launch_bounds__(256) void k_gemm_y(
    const float* __restrict__ enc,
    const float* __restrict__ Wm, const float* __restrict__ bm,
    float* __restrict__ y)
{
  __shared__ float A[BM][68];
  const int tid = threadIdx.x;
  const int m0  = blockIdx.x * BM;
  const int tx = tid & 15, ty = tid >> 4;
  const int r = tid >> 2, part = tid & 3;
  float acc[4][16] = {};

  for (int kc = 0; kc < 4; ++kc) {
    __syncthreads();
    const float4* s4 = (const float4*)(enc + (size_t)(m0 + r) * 256 + kc * 64 + part * 16);
    float4 v0 = s4[0], v1 = s4[1], v2 = s4[2], v3 = s4[3];
    float4* d4 = (float4*)&A[r][part * 16];
    d4[0] = v0; d4[1] = v1; d4[2] = v2; d4[3] = v3;
    __syncthreads();
    const float* wbase = Wm + (size_t)(kc * 64) * 256 + tx * 16;
    for (int k = 0; k < 64; ++k) {
      float wv[16];
      load_w16(wbase + (size_t)k * 256, wv);
      float av[4];
#pragma unroll
      for (int i = 0; i < 4; ++i) av[i] = A[ty * 4 + i][k];
      fma_tile(acc, av, wv);
    }
  }

  float bv[16];
  load_w16(bm + tx * 16, bv);
#pragma unroll
  for (int i = 0; i < 4; ++i) {
    float* out = y + (size_t)(m0 + ty * 4 + i) * 256 + tx * 16;
#pragma unroll
    for (int j = 0; j < 16; j += 4) {
      float4 o4;
      o4.x = acc[i][j + 0] + bv[j + 0];
      o4.y = acc[i][j + 1] + bv[j + 1];
      o4.z = acc[i][j + 2] + bv[j + 2];
      o4.w = acc[i][j + 3] + bv[j + 3];
      *(float4*)(out + j) = o4;
    }
  }
}

// ---------------------------------------------------------------------------
// K-reduce2: agg[d] = sum_{e in CSR(d)} relu(y[src_e] + rel @ Wm_rel)
// ---------------------------------------------------------------------------
__global__ __launch_bounds__(256) void k_reduce2(
    const float* __restrict__ y, const float* __restrict__ agent_pos,
    const int* __restrict__ rp, const int* __restrict__ sorted_src,
    const float* __restrict__ Wm, float* __restrict__ agg)
{
  const int d    = blockIdx.x * 4 + (threadIdx.x >> 6);
  const int lane = threadIdx.x & 63;
  const float dx = agent_pos[(size_t)d * 2 + 0];
  const float dy = agent_pos[(size_t)d * 2 + 1];
  const float4 w0 = *(const float4*)(Wm + (size_t)256 * 256 + lane * 4);
  const float4 w1 = *(const float4*)(Wm + (size_t)257 * 256 + lane * 4);
  float4 acc = {0.f, 0.f, 0.f, 0.f};
  const int e0 = rp[d], e1 = rp[d + 1];
  for (int i = e0; i < e1; ++i) {
    const int s = sorted_src[i];
    const float relx = agent_pos[(size_t)s * 2 + 0] - dx;
    const float rely = agent_pos[(size_t)s * 2 + 1] - dy;
    float4 v = *(const float4*)(y + (size_t)s * 256 + lane * 4);
    acc.x += fmaxf(v.x + relx * w0.x + rely * w1.x, 0.f);
    acc.y += fmaxf(v.y + relx * w0.y + rely * w1.y, 0.f);
    acc.z += fmaxf(v.z + relx * w0.z + rely * w1.z, 0.f);
    acc.w += fmaxf(v.w + relx * w0.w + rely * w1.w, 0.f);
  }
  *(float4*)(agg + (size_t)d * 256 + lane * 4) = acc;
}

// ---------------------------------------------------------------------------
// K-upd: x = relu(concat(enc, agg) @ W_upd + bu)
// ---------------------------------------------------------------------------
__global__ __launch_bounds__(256) void k_upd(
    const float* __restrict__ enc, const float* __restrict__ agg,
    const float* __restrict__ Wu, const float* __restrict__ bu,
    float* __restrict__ x)
{
  __shared__ float A[BM][68];
  const int tid = threadIdx.x;
  const int m0  = blockIdx.x * BM;
  const int tx = tid & 15, ty = tid >> 4;
  const int r = tid >> 2, part = tid & 3;
  float acc[4][16] = {};

  for (int kc = 0; kc < 8; ++kc) {
    const float* base = (kc < 4) ? enc : agg;
    const int ko = (kc & 3) * 64;
    __syncthreads();
    const float4* s4 = (const float4*)(base + (size_t)(m0 + r) * 256 + ko + part * 16);
    float4 v0 = s4[0], v1 = s4[1], v2 = s4[2], v3 = s4[3];
    float4* d4 = (float4*)&A[r][part * 16];
    d4[0] = v0; d4[1] = v1; d4[2] = v2; d4[3] = v3;
    __syncthreads();
    const float* wbase = Wu + (size_t)(kc * 64) * 256 + tx * 16;
    for (int k = 0; k < 64; ++k) {
      float wv[16];
      load_w16(wbase + (size_t)k * 256, wv);
      float av[4];
#pragma unroll
      for (int i = 0; i < 4; ++i) av[i] = A[ty * 4 + i][k];
      fma_tile(acc, av, wv);
    }
  }

  float bv[16];
  load_w16(bu + tx * 16, bv);
#pragma unroll
  for (int i = 0; i < 4; ++i) {
    float* out = x + (size_t)(m0 + ty * 4 + i) * 256 + tx * 16;
#pragma unroll
    for (int j = 0; j < 16; j += 4) {
      float4 o4;
      o4.x = fmaxf(acc[i][j + 0] + bv[j + 0], 0.f);
      o4.y = fmaxf(acc[i][j + 1] + bv[j + 1], 0.f);
      o4.z = fmaxf(acc[i][j + 2] + bv[j + 2], 0.f);
      o4.w = fmaxf(acc[i][j + 3] + bv[j + 3], 0.f);
      *(float4*)(out + j) = o4;
    }
  }
}

// ---------------------------------------------------------------------------
// K-dec: decoded = x @ W_dec + bd  -> out[0 : NA*1056)
// ---------------------------------------------------------------------------
__global__ __launch_bounds__(256) void k_dec(
    const float* __restrict__ x,
    const float* __restrict__ Wd, const float* __restrict__ bd,
    float* __restrict__ out)
{
  __shared__ float A[BM][68];
  const int tid = threadIdx.x;
  const int m0  = blockIdx.x * BM;
  const int n0  = blockIdx.y * 256;
  const int tx = tid & 15, ty = tid >> 4;
  const int r = tid >> 2, part = tid & 3;

  int c0 = n0 + tx * 16;
  const bool active = (c0 < NDEC);
  if (c0 > NDEC - 16) c0 = NDEC - 16;

  float acc[4][16] = {};
  for (int kc = 0; kc < 4; ++kc) {
    __syncthreads();
    const float4* s4 = (const float4*)(x + (size_t)(m0 + r) * 256 + kc * 64 + part * 16);
    float4 v0 = s4[0], v1 = s4[1], v2 = s4[2], v3 = s4[3];
    float4* d4 = (float4*)&A[r][part * 16];
    d4[0] = v0; d4[1] = v1; d4[2] = v2; d4[3] = v3;
    __syncthreads();
    const float* wbase = Wd + (size_t)(kc * 64) * NDEC + c0;
    for (int k = 0; k < 64; ++k) {
      float wv[16];
      load_w16(wbase + (size_t)k * NDEC, wv);
      float av[4];
#pragma unroll
      for (int i = 0; i < 4; ++i) av[i] = A[ty * 4 + i][k];
      fma_tile(acc, av, wv);
    }
  }

  if (active) {
    float bv[16];
    load_w16(bd + c0, bv);
#pragma unroll
    for (int i = 0; i < 4; ++i) {
      float* o = out + (size_t)(m0 + ty * 4 + i) * NDEC + c0;
#pragma unroll
      for (int j = 0; j < 16; j += 4) {
        float4 o4;
        o4.x = acc[i][j + 0] + bv[j + 0];
        o4.y = acc[i][j + 1] + bv[j + 1];
        o4.z = acc[i][j + 2] + bv[j + 2];
        o4.w = acc[i][j + 3] + bv[j + 3];
        *(float4*)(o + j) = o4;
      }
    }
  }
}

// ---------------------------------------------------------------------------
// K-batch: batch[i] = i >> 4 (float out)
// ---------------------------------------------------------------------------
__global__ __launch_bounds__(256) void k_batch(float* __restrict__ out)
{
  const int i = blockIdx.x * 256 + threadIdx.x;
  out[DEC_OFF + (size_t)i] = (float)(i >> 4);
}

// ---------------------------------------------------------------------------
extern "C" void kernel_launch(void* const* d_in, const int* in_sizes, int n_in,
                              void* d_out, int out_size, void* d_ws, size_t ws_size,
                              hipStream_t stream) {
  const float* obj_x     = (const float*)d_in[0];
  const float* obj_pos   = (const float*)d_in[1];
  const float* agent_pos = (const float*)d_in[2];
  const int*   oae       = (const int*)d_in[3];   // [2][E1]: row0 agent, row1 obj
  const int*   ae        = (const int*)d_in[4];   // [2][E2]: row0 src, row1 dst
  const float* W1 = (const float*)d_in[5];
  const float* b1 = (const float*)d_in[6];
  const float* W2 = (const float*)d_in[7];
  const float* b2 = (const float*)d_in[8];
  const float* Wm = (const float*)d_in[9];
  const float* bm = (const float*)d_in[10];
  const float* Wu = (const float*)d_in[11];
  const float* bu = (const float*)d_in[12];
  const float* Wd = (const float*)d_in[13];
  const float* bd = (const float*)d_in[14];
  float* out = (float*)d_out;

  const int* agent_idx = oae;            // obs: key = agent
  const int* obj_idx   = oae + E1CNT;
  const int* src       = ae;             // comm: key = dst, val = src
  const int* dst       = ae + E2CNT;

  // ---- workspace layout (aliased by phase) -------------------------------
  // bufA [NOBJ*256 floats = 33.55MB]: zobj  -> later enc (low 16MB) + y/xb (high 16MB)
  // bufB [NA*256 floats  = 16.78MB]: s1    -> later agg
  // then int region: rp1[16385] cur1[16384] rp2[16385] cur2[16384]
  //                  sorted_obj[E1] sorted_src[E2]
  float* bufA = (float*)d_ws;
  float* zobj = bufA;
  float* enc  = bufA;
  float* ybuf = bufA + (size_t)NA * 256;
  float* xb   = bufA + (size_t)NA * 256;   // reuses y after reduce2
  float* bufB = bufA + (size_t)NOBJ * 256;
  float* s1   = bufB;
  float* agg  = bufB;
  int* rp1  = (int*)(bufB + (size_t)NA * 256);
  int* cur1 = rp1 + (NA + 1);
  int* rp2  = cur1 + NA;
  int* cur2 = rp2 + (NA + 1);
  int* sorted_obj = cur2 + NA;
  int* sorted_src = sorted_obj + E1CNT;

  // ---- CSR build ----------------------------------------------------------
  hipMemsetAsync(cur1, 0, (size_t)NA * sizeof(int), stream);
  hipMemsetAsync(cur2, 0, (size_t)NA * sizeof(int), stream);
  k_count<<<E1CNT / 256, 256, 0, stream>>>(agent_idx, E1CNT, cur1);
  k_count<<<E2CNT / 256, 256, 0, stream>>>(dst, E2CNT, cur2);
  k_scan<<<2, 256, 0, stream>>>(cur1, rp1, cur2, rp2);
  k_fill<<<E1CNT / 256, 256, 0, stream>>>(agent_idx, obj_idx, E1CNT, cur1, sorted_obj);
  k_fill<<<E2CNT / 256, 256, 0, stream>>>(dst, src, E2CNT, cur2, sorted_src);

  // ---- encode -------------------------------------------------------------
  k_zobj<<<NOBJ / 64, 256, 0, stream>>>(obj_x, obj_pos, W1, b1, zobj);
  k_reduce1<<<NA / 4, 256, 0, stream>>>(zobj, agent_pos, rp1, sorted_obj, W1, s1);
  k_gemm_enc<<<NA / 64, 256, 0, stream>>>(s1, W2, b2, rp1, enc);

  // ---- merge --------------------------------------------------------------
  k_gemm_y<<<NA / 64, 256, 0, stream>>>(enc, Wm, bm, ybuf);
  k_reduce2<<<NA / 4, 256, 0, stream>>>(ybuf, agent_pos, rp2, sorted_src, Wm, agg);
  k_upd<<<NA / 64, 256, 0, stream>>>(enc, agg, Wu, bu, xb);

  // ---- decode -------------------------------------------------------------
  k_dec<<<dim3(NA / 64, 5), 256, 0, stream>>>(xb, Wd, bd, out);
  k_batch<<<(NA * 16) / 256, 256, 0, stream>>>(out);
}

// Round 3
// 350.496 us; speedup vs baseline: 19.0324x; 2.6098x over previous
//
#include <hip/hip_runtime.h>
#include <cstdint>
#include <cstddef>

#define EMB   256
#define NA    16384
#define NOBJ  32768
#define E1CNT 131072
#define E2CNT 262144
#define NDEC  1056
#define NDECP 1152
#define DEC_OFF ((size_t)NA * NDEC)

typedef unsigned short u16;
typedef __attribute__((ext_vector_type(8))) short bf16x8;
typedef __attribute__((ext_vector_type(4))) float f32x4;

// ---------------------------------------------------------------------------
// bf16 helpers (RNE)
// ---------------------------------------------------------------------------
__device__ __forceinline__ u16 f2bf(float f) {
  union { float f; unsigned u; } x; x.f = f;
  unsigned u = x.u + 0x7FFFu + ((x.u >> 16) & 1u);
  return (u16)(u >> 16);
}
__device__ __forceinline__ float bf2f(u16 h) {
  union { unsigned u; float f; } x; x.u = ((unsigned)h) << 16;
  return x.f;
}

__device__ __forceinline__ void gload_lds16(const void* g, void* l) {
  __builtin_amdgcn_global_load_lds(
      (const __attribute__((address_space(1))) unsigned int*)g,
      (__attribute__((address_space(3))) unsigned int*)l, 16, 0, 0);
}

// ---------------------------------------------------------------------------
// CSR build: count / scan / fill (verified round 2)
// ---------------------------------------------------------------------------
__global__ __launch_bounds__(256) void k_count(const int* __restrict__ key, int n,
                                               int* __restrict__ cnt) {
  int e = blockIdx.x * 256 + threadIdx.x;
  if (e < n) atomicAdd(&cnt[key[e]], 1);
}

__global__ __launch_bounds__(256) void k_scan(int* c1, int* r1, int* c2, int* r2) {
  int* cnt = (blockIdx.x == 0) ? c1 : c2;
  int* rp  = (blockIdx.x == 0) ? r1 : r2;
  const int n = NA;
  __shared__ int partial[256];
  const int tid = threadIdx.x;
  const int base = tid * 64;
  int local[64];
  int s = 0;
#pragma unroll
  for (int i = 0; i < 64; ++i) { local[i] = s; s += cnt[base + i]; }
  partial[tid] = s;
  __syncthreads();
  for (int off = 1; off < 256; off <<= 1) {
    int v = (tid >= off) ? partial[tid - off] : 0;
    __syncthreads();
    partial[tid] += v;
    __syncthreads();
  }
  const int offset = (tid == 0) ? 0 : partial[tid - 1];
#pragma unroll
  for (int i = 0; i < 64; ++i) {
    int v = offset + local[i];
    rp[base + i]  = v;
    cnt[base + i] = v;
  }
  if (tid == 255) rp[n] = partial[255];
}

__global__ __launch_bounds__(256) void k_fill(const int* __restrict__ key,
                                              const int* __restrict__ val, int n,
                                              int* __restrict__ cursor,
                                              int* __restrict__ out) {
  int e = blockIdx.x * 256 + threadIdx.x;
  if (e < n) {
    int p = atomicAdd(&cursor[key[e]], 1);
    out[p] = val[e];
  }
}

// ---------------------------------------------------------------------------
// prep: Aobj[o][96] bf16 = [obj_x | obj_pos | 0-pad]
// grid NOBJ/8, block 768 (8 rows x 96 cols)
// ---------------------------------------------------------------------------
__global__ __launch_bounds__(768) void k_prep_obj(
    const float* __restrict__ obj_x, const float* __restrict__ obj_pos,
    u16* __restrict__ Aobj)
{
  const int tid = threadIdx.x;
  const int r = tid / 96, c = tid - r * 96;
  const int row = blockIdx.x * 8 + r;
  float v = 0.f;
  if (c < 64)      v = obj_x[(size_t)row * 64 + c];
  else if (c < 66) v = obj_pos[(size_t)row * 2 + (c - 64)];
  Aobj[(size_t)row * 96 + c] = f2bf(v);
}

// ---------------------------------------------------------------------------
// weight transpose + bf16 + pad: WT[n][Kpad] = W[k][No] (zeros outside)
// grid ((Kpad+127)/128, NT), block 128
// ---------------------------------------------------------------------------
__global__ __launch_bounds__(128) void k_cvt(const float* __restrict__ W,
                                             u16* __restrict__ WT,
                                             int Ko, int No, int Kpad)
{
  const int k = blockIdx.x * 128 + threadIdx.x;
  const int n = blockIdx.y;
  if (k >= Kpad) return;
  float v = (k < Ko && n < No) ? W[(size_t)k * No + n] : 0.f;
  WT[(size_t)n * Kpad + k] = f2bf(v);
}

// ---------------------------------------------------------------------------
// generic MFMA GEMM: D = A @ WT^T (+epilogue)
// A bf16 row-major [M][lda] (A2 takes over at k >= ksw), BT bf16 [N][ktot]
// 128x128 tile, 4 waves, BK=32, global_load_lds staging
// mode: 0 = +bias -> bf16 | 1 = +deg*bias -> bf16 | 2 = relu(+bias) -> bf16
//       3 = +bias -> fp32, col-guarded by nmax
// ---------------------------------------------------------------------------
__global__ __launch_bounds__(256) void k_mfma(
    const u16* __restrict__ A1, const u16* __restrict__ A2, int lda,
    const u16* __restrict__ BT, int ktot, int ksw,
    const float* __restrict__ bias, const int* __restrict__ rp, int mode,
    u16* __restrict__ out16, float* __restrict__ out32, int ldo, int nmax)
{
  __shared__ u16 As[128 * 32];
  __shared__ u16 Bs[128 * 32];
  const int tid  = threadIdx.x;
  const int lane = tid & 63;
  const int wave = tid >> 6;
  const int m0 = blockIdx.x * 128;
  const int n0 = blockIdx.y * 128;
  const int wm = wave & 1, wn = wave >> 1;

  f32x4 acc[4][4];
#pragma unroll
  for (int i = 0; i < 4; ++i)
#pragma unroll
    for (int j = 0; j < 4; ++j) {
      acc[i][j][0] = 0.f; acc[i][j][1] = 0.f; acc[i][j][2] = 0.f; acc[i][j][3] = 0.f;
    }

  const int nk = ktot / 32;
  const int wbase = tid & ~63;          // wave-uniform
  for (int kc = 0; kc < nk; ++kc) {
    const u16* Ab; int kof;
    if (kc * 32 < ksw) { Ab = A1; kof = kc * 32; }
    else               { Ab = A2; kof = kc * 32 - ksw; }
    __syncthreads();
#pragma unroll
    for (int r = 0; r < 2; ++r) {
      const int u = r * 256 + tid;
      const int row = u >> 2, part = u & 3;
      gload_lds16(Ab + (size_t)(m0 + row) * lda + kof + part * 8,
                  As + (size_t)(r * 256 + wbase) * 8);
      gload_lds16(BT + (size_t)(n0 + row) * ktot + kc * 32 + part * 8,
                  Bs + (size_t)(r * 256 + wbase) * 8);
    }
    __syncthreads();
    bf16x8 a[4], b[4];
#pragma unroll
    for (int i = 0; i < 4; ++i)
      a[i] = *(const bf16x8*)&As[(wm * 64 + 16 * i + (lane & 15)) * 32 + (lane >> 4) * 8];
#pragma unroll
    for (int j = 0; j < 4; ++j)
      b[j] = *(const bf16x8*)&Bs[(wn * 64 + 16 * j + (lane & 15)) * 32 + (lane >> 4) * 8];
#pragma unroll
    for (int i = 0; i < 4; ++i)
#pragma unroll
      for (int j = 0; j < 4; ++j)
        acc[i][j] = __builtin_amdgcn_mfma_f32_16x16x32_bf16(a[i], b[j], acc[i][j], 0, 0, 0);
  }

  // epilogue: C/D layout col=lane&15, row=(lane>>4)*4+reg
#pragma unroll
  for (int i = 0; i < 4; ++i) {
    const int rbase = m0 + wm * 64 + 16 * i + (lane >> 4) * 4;
    float deg[4];
    if (mode == 1) {
#pragma unroll
      for (int r = 0; r < 4; ++r)
        deg[r] = (float)(rp[rbase + r + 1] - rp[rbase + r]);
    }
#pragma unroll
    for (int j = 0; j < 4; ++j) {
      const int c = n0 + wn * 64 + 16 * j + (lane & 15);
      const float bv = (c < nmax) ? bias[c] : 0.f;
#pragma unroll
      for (int r = 0; r < 4; ++r) {
        float v = acc[i][j][r];
        if (mode == 1) v += deg[r] * bv; else v += bv;
        if (mode == 2) v = fmaxf(v, 0.f);
        const size_t row = (size_t)(rbase + r);
        if (mode == 3) {
          if (c < nmax) out32[row * ldo + c] = v;
        } else {
          out16[row * ldo + c] = f2bf(v);
        }
      }
    }
  }
}

// ---------------------------------------------------------------------------
// reduce1: s1[a] = sum_e relu(zobj[obj_e] - agent_pos[a] @ W1[64:66])  (bf16 io)
// one wave per agent, lane owns 4 cols
// ---------------------------------------------------------------------------
__global__ __launch_bounds__(256) void k_reduce1(
    const u16* __restrict__ zobj, const float* __restrict__ agent_pos,
    const int* __restrict__ rp, const int* __restrict__ sorted_obj,
    const float* __restrict__ W1, u16* __restrict__ s1)
{
  const int a    = blockIdx.x * 4 + (threadIdx.x >> 6);
  const int lane = threadIdx.x & 63;
  const float ax = agent_pos[(size_t)a * 2 + 0];
  const float ay = agent_pos[(size_t)a * 2 + 1];
  const float4 w0 = *(const float4*)(W1 + (size_t)64 * 256 + lane * 4);
  const float4 w1 = *(const float4*)(W1 + (size_t)65 * 256 + lane * 4);
  const float t0 = ax * w0.x + ay * w1.x;
  const float t1 = ax * w0.y + ay * w1.y;
  const float t2 = ax * w0.z + ay * w1.z;
  const float t3 = ax * w0.w + ay * w1.w;
  float a0 = 0.f, a1 = 0.f, a2 = 0.f, a3 = 0.f;
  const int e0 = rp[a], e1 = rp[a + 1];
  for (int i = e0; i < e1; ++i) {
    const int o = sorted_obj[i];
    const ushort4 z = *(const ushort4*)(zobj + (size_t)o * 256 + lane * 4);
    a0 += fmaxf(bf2f(z.x) - t0, 0.f);
    a1 += fmaxf(bf2f(z.y) - t1, 0.f);
    a2 += fmaxf(bf2f(z.z) - t2, 0.f);
    a3 += fmaxf(bf2f(z.w) - t3, 0.f);
  }
  ushort4 o4; o4.x = f2bf(a0); o4.y = f2bf(a1); o4.z = f2bf(a2); o4.w = f2bf(a3);
  *(ushort4*)(s1 + (size_t)a * 256 + lane * 4) = o4;
}

// ---------------------------------------------------------------------------
// reduce2: agg[d] = sum_e relu(y[src_e] + rel @ Wm[256:258])  (bf16 io)
// ---------------------------------------------------------------------------
__global__ __launch_bounds__(256) void k_reduce2(
    const u16* __restrict__ y, const float* __restrict__ agent_pos,
    const int* __restrict__ rp, const int* __restrict__ sorted_src,
    const float* __restrict__ Wm, u16* __restrict__ agg)
{
  const int d    = blockIdx.x * 4 + (threadIdx.x >> 6);
  const int lane = threadIdx.x & 63;
  const float dx = agent_pos[(size_t)d * 2 + 0];
  const float dy = agent_pos[(size_t)d * 2 + 1];
  const float4 w0 = *(const float4*)(Wm + (size_t)256 * 256 + lane * 4);
  const float4 w1 = *(const float4*)(Wm + (size_t)257 * 256 + lane * 4);
  float a0 = 0.f, a1 = 0.f, a2 = 0.f, a3 = 0.f;
  const int e0 = rp[d], e1 = rp[d + 1];
  for (int i = e0; i < e1; ++i) {
    const int s = sorted_src[i];
    const float rx = agent_pos[(size_t)s * 2 + 0] - dx;
    const float ry = agent_pos[(size_t)s * 2 + 1] - dy;
    const ushort4 v = *(const ushort4*)(y + (size_t)s * 256 + lane * 4);
    a0 += fmaxf(bf2f(v.x) + rx * w0.x + ry * w1.x, 0.f);
    a1 += fmaxf(bf2f(v.y) + rx * w0.y + ry * w1.y, 0.f);
    a2 += fmaxf(bf2f(v.z) + rx * w0.z + ry * w1.z, 0.f);
    a3 += fmaxf(bf2f(v.w) + rx * w0.w + ry * w1.w, 0.f);
  }
  ushort4 o4; o4.x = f2bf(a0); o4.y = f2bf(a1); o4.z = f2bf(a2); o4.w = f2bf(a3);
  *(ushort4*)(agg + (size_t)d * 256 + lane * 4) = o4;
}

// ---------------------------------------------------------------------------
// batch[i] = i >> 4
// ---------------------------------------------------------------------------
__global__ __launch_bounds__(256) void k_batch(float* __restrict__ out)
{
  const int i = blockIdx.x * 256 + threadIdx.x;
  out[DEC_OFF + (size_t)i] = (float)(i >> 4);
}

// ---------------------------------------------------------------------------
extern "C" void kernel_launch(void* const* d_in, const int* in_sizes, int n_in,
                              void* d_out, int out_size, void* d_ws, size_t ws_size,
                              hipStream_t stream) {
  const float* obj_x     = (const float*)d_in[0];
  const float* obj_pos   = (const float*)d_in[1];
  const float* agent_pos = (const float*)d_in[2];
  const int*   oae       = (const int*)d_in[3];
  const int*   ae        = (const int*)d_in[4];
  const float* W1 = (const float*)d_in[5];
  const float* b1 = (const float*)d_in[6];
  const float* W2 = (const float*)d_in[7];
  const float* b2 = (const float*)d_in[8];
  const float* Wm = (const float*)d_in[9];
  const float* bm = (const float*)d_in[10];
  const float* Wu = (const float*)d_in[11];
  const float* bu = (const float*)d_in[12];
  const float* Wd = (const float*)d_in[13];
  const float* bd = (const float*)d_in[14];
  float* out = (float*)d_out;

  const int* agent_idx = oae;
  const int* obj_idx   = oae + E1CNT;
  const int* src       = ae;
  const int* dst       = ae + E2CNT;

  // ---- workspace: slabA (Aobj -> s1 -> xb) | slabZ (zobj -> y|agg) | enc |
  //                 weight bf16 | CSR ints                       (~36.6 MB)
  char* p = (char*)d_ws;
  u16* slabA = (u16*)p; p += (size_t)NA * 256 * 2;      // 8.39 MB (Aobj: NOBJ*96 fits)
  u16* slabZ = (u16*)p; p += (size_t)NOBJ * 256 * 2;    // 16.78 MB
  u16* enc   = (u16*)p; p += (size_t)NA * 256 * 2;      // 8.39 MB
  u16* w1t = (u16*)p; p += (size_t)256 * 96 * 2;
  u16* w2t = (u16*)p; p += (size_t)256 * 256 * 2;
  u16* wmt = (u16*)p; p += (size_t)256 * 256 * 2;
  u16* wut = (u16*)p; p += (size_t)256 * 512 * 2;
  u16* wdt = (u16*)p; p += (size_t)NDECP * 256 * 2;
  int* rp1  = (int*)p;           p += (size_t)(NA + 1) * 4;
  int* cur1 = (int*)p;           p += (size_t)NA * 4;
  int* rp2  = (int*)p;           p += (size_t)(NA + 1) * 4;
  int* cur2 = (int*)p;           p += (size_t)NA * 4;
  int* sorted_obj = (int*)p;     p += (size_t)E1CNT * 4;
  int* sorted_src = (int*)p;

  u16* Aobj = slabA;
  u16* s1   = slabA;
  u16* xb   = slabA;
  u16* zobj = slabZ;
  u16* ybuf = slabZ;
  u16* agg  = slabZ + (size_t)NA * 256;

  const int BIG = 1 << 30;

  // ---- CSR ---------------------------------------------------------------
  hipMemsetAsync(cur1, 0, (size_t)NA * sizeof(int), stream);
  hipMemsetAsync(cur2, 0, (size_t)NA * sizeof(int), stream);
  k_count<<<E1CNT / 256, 256, 0, stream>>>(agent_idx, E1CNT, cur1);
  k_count<<<E2CNT / 256, 256, 0, stream>>>(dst, E2CNT, cur2);
  k_scan<<<2, 256, 0, stream>>>(cur1, rp1, cur2, rp2);
  k_fill<<<E1CNT / 256, 256, 0, stream>>>(agent_idx, obj_idx, E1CNT, cur1, sorted_obj);
  k_fill<<<E2CNT / 256, 256, 0, stream>>>(dst, src, E2CNT, cur2, sorted_src);

  // ---- bf16 conversions --------------------------------------------------
  k_prep_obj<<<NOBJ / 8, 768, 0, stream>>>(obj_x, obj_pos, Aobj);
  k_cvt<<<dim3(1, 256),   128, 0, stream>>>(W1, w1t,  66,  256,  96);
  k_cvt<<<dim3(2, 256),   128, 0, stream>>>(W2, w2t, 256,  256, 256);
  k_cvt<<<dim3(2, 256),   128, 0, stream>>>(Wm, wmt, 256,  256, 256);
  k_cvt<<<dim3(4, 256),   128, 0, stream>>>(Wu, wut, 512,  256, 512);
  k_cvt<<<dim3(2, NDECP), 128, 0, stream>>>(Wd, wdt, 256, NDEC, 256);

  // ---- encode ------------------------------------------------------------
  k_mfma<<<dim3(NOBJ / 128, 2), 256, 0, stream>>>(
      Aobj, Aobj, 96, w1t, 96, BIG, b1, nullptr, 0, zobj, nullptr, 256, 256);
  k_reduce1<<<NA / 4, 256, 0, stream>>>(zobj, agent_pos, rp1, sorted_obj, W1, s1);
  k_mfma<<<dim3(NA / 128, 2), 256, 0, stream>>>(
      s1, s1, 256, w2t, 256, BIG, b2, rp1, 1, enc, nullptr, 256, 256);

  // ---- merge -------------------------------------------------------------
  k_mfma<<<dim3(NA / 128, 2), 256, 0, stream>>>(
      enc, enc, 256, wmt, 256, BIG, bm, nullptr, 0, ybuf, nullptr, 256, 256);
  k_reduce2<<<NA / 4, 256, 0, stream>>>(ybuf, agent_pos, rp2, sorted_src, Wm, agg);
  k_mfma<<<dim3(NA / 128, 2), 256, 0, stream>>>(
      enc, agg, 256, wut, 512, 256, bu, nullptr, 2, xb, nullptr, 256, 256);

  // ---- decode ------------------------------------------------------------
  k_mfma<<<dim3(NA / 128, NDECP / 128), 256, 0, stream>>>(
      xb, xb, 256, wdt, 256, BIG, bd, nullptr, 3, nullptr, out, NDEC, NDEC);
  k_batch<<<(NA * 16) / 256, 256, 0, stream>>>(out);
}

// Round 4
// 295.391 us; speedup vs baseline: 22.5829x; 1.1866x over previous
//
#include <hip/hip_runtime.h>
#include <cstdint>
#include <cstddef>

#define EMB   256
#define NA    16384
#define NOBJ  32768
#define E1CNT 131072
#define E2CNT 262144
#define NDEC  1056
#define NDECP 1152
#define DEC_OFF ((size_t)NA * NDEC)

typedef unsigned short u16;
typedef __attribute__((ext_vector_type(8))) short bf16x8;
typedef __attribute__((ext_vector_type(4))) float f32x4;

// ---------------------------------------------------------------------------
// bf16 helpers (RNE)
// ---------------------------------------------------------------------------
__device__ __forceinline__ u16 f2bf(float f) {
  union { float f; unsigned u; } x; x.f = f;
  unsigned u = x.u + 0x7FFFu + ((x.u >> 16) & 1u);
  return (u16)(u >> 16);
}
__device__ __forceinline__ float bf2f(u16 h) {
  union { unsigned u; float f; } x; x.u = ((unsigned)h) << 16;
  return x.f;
}

__device__ __forceinline__ void gload_lds16(const void* g, void* l) {
  __builtin_amdgcn_global_load_lds(
      (const __attribute__((address_space(1))) unsigned int*)g,
      (__attribute__((address_space(3))) unsigned int*)l, 16, 0, 0);
}

// ---------------------------------------------------------------------------
// CSR build: fused count / scan / fused fill
// ---------------------------------------------------------------------------
__global__ __launch_bounds__(256) void k_count_all(
    const int* __restrict__ k1, const int* __restrict__ k2,
    int* __restrict__ c1, int* __restrict__ c2) {
  int e = blockIdx.x * 256 + threadIdx.x;
  if (e < E1CNT) atomicAdd(&c1[k1[e]], 1);
  else           atomicAdd(&c2[k2[e - E1CNT]], 1);
}

__global__ __launch_bounds__(256) void k_scan(int* c1, int* r1, int* c2, int* r2) {
  int* cnt = (blockIdx.x == 0) ? c1 : c2;
  int* rp  = (blockIdx.x == 0) ? r1 : r2;
  const int n = NA;
  __shared__ int partial[256];
  const int tid = threadIdx.x;
  const int base = tid * 64;
  int local[64];
  int s = 0;
#pragma unroll
  for (int i = 0; i < 64; ++i) { local[i] = s; s += cnt[base + i]; }
  partial[tid] = s;
  __syncthreads();
  for (int off = 1; off < 256; off <<= 1) {
    int v = (tid >= off) ? partial[tid - off] : 0;
    __syncthreads();
    partial[tid] += v;
    __syncthreads();
  }
  const int offset = (tid == 0) ? 0 : partial[tid - 1];
#pragma unroll
  for (int i = 0; i < 64; ++i) {
    int v = offset + local[i];
    rp[base + i]  = v;
    cnt[base + i] = v;
  }
  if (tid == 255) rp[n] = partial[255];
}

__global__ __launch_bounds__(256) void k_fill_all(
    const int* __restrict__ k1, const int* __restrict__ v1,
    const int* __restrict__ k2, const int* __restrict__ v2,
    int* __restrict__ cur1, int* __restrict__ cur2,
    int* __restrict__ o1, int* __restrict__ o2) {
  int e = blockIdx.x * 256 + threadIdx.x;
  if (e < E1CNT) {
    int p = atomicAdd(&cur1[k1[e]], 1);
    o1[p] = v1[e];
  } else {
    int i = e - E1CNT;
    int p = atomicAdd(&cur2[k2[i]], 1);
    o2[p] = v2[i];
  }
}

// ---------------------------------------------------------------------------
// prep: Aobj[o][96] bf16 = [obj_x | obj_pos | 0-pad]; grid NOBJ/8, block 768
// ---------------------------------------------------------------------------
__global__ __launch_bounds__(768) void k_prep_obj(
    const float* __restrict__ obj_x, const float* __restrict__ obj_pos,
    u16* __restrict__ Aobj)
{
  const int tid = threadIdx.x;
  const int r = tid / 96, c = tid - r * 96;
  const int row = blockIdx.x * 8 + r;
  float v = 0.f;
  if (c < 64)      v = obj_x[(size_t)row * 64 + c];
  else if (c < 66) v = obj_pos[(size_t)row * 2 + (c - 64)];
  Aobj[(size_t)row * 96 + c] = f2bf(v);
}

// ---------------------------------------------------------------------------
// all weights: transpose + bf16 + pad in ONE kernel.
// flat layout (WT order, n-major): seg sizes 24576|65536|65536|131072|294912
// ---------------------------------------------------------------------------
__global__ __launch_bounds__(256) void k_cvt_all(
    const float* __restrict__ W1, const float* __restrict__ W2,
    const float* __restrict__ Wm, const float* __restrict__ Wu,
    const float* __restrict__ Wd,
    u16* __restrict__ w1t, u16* __restrict__ w2t, u16* __restrict__ wmt,
    u16* __restrict__ wut, u16* __restrict__ wdt)
{
  int g = blockIdx.x * 256 + threadIdx.x;
  const float* W; u16* WT; int Ko, No, Kpad, local;
  if (g < 24576)       { W = W1; WT = w1t; Ko = 66;  No = 256;  Kpad = 96;  local = g; }
  else if (g < 90112)  { W = W2; WT = w2t; Ko = 256; No = 256;  Kpad = 256; local = g - 24576; }
  else if (g < 155648) { W = Wm; WT = wmt; Ko = 256; No = 256;  Kpad = 256; local = g - 90112; }
  else if (g < 286720) { W = Wu; WT = wut; Ko = 512; No = 256;  Kpad = 512; local = g - 155648; }
  else                 { W = Wd; WT = wdt; Ko = 256; No = 1056; Kpad = 256; local = g - 286720; }
  const int n = local / Kpad, k = local - n * Kpad;
  float v = (k < Ko && n < No) ? W[(size_t)k * No + n] : 0.f;
  WT[(size_t)n * Kpad + k] = f2bf(v);
}

// ---------------------------------------------------------------------------
// generic MFMA GEMM, templated tile: BMT x BNT, wave grid WM x WN (WM*WN=4)
// A bf16 [M][lda] (A2 takes over at k >= ksw), BT bf16 [N][ktot]
// mode: 0 = +bias -> bf16 | 1 = +deg*bias -> bf16 | 2 = relu(+bias) -> bf16
//       3 = +bias -> fp32 col-guarded by nmax, + fused batch write (blockIdx.y==0)
// ---------------------------------------------------------------------------
template<int BMT, int BNT, int WM, int WN>
__global__ __launch_bounds__(256) void k_mfma(
    const u16* __restrict__ A1, const u16* __restrict__ A2, int lda,
    const u16* __restrict__ BT, int ktot, int ksw,
    const float* __restrict__ bias, const int* __restrict__ rp, int mode,
    u16* __restrict__ out16, float* __restrict__ out32, int ldo, int nmax)
{
  constexpr int FI = BMT / (WM * 16);
  constexpr int FJ = BNT / (WN * 16);
  constexpr int RA = BMT * 4 / 256;
  constexpr int RB = BNT * 4 / 256;
  __shared__ u16 As[BMT * 32];
  __shared__ u16 Bs[BNT * 32];
  const int tid  = threadIdx.x;
  const int lane = tid & 63;
  const int wave = tid >> 6;
  const int m0 = blockIdx.x * BMT;
  const int n0 = blockIdx.y * BNT;
  const int wm = wave % WM, wn = wave / WM;

  f32x4 acc[FI][FJ];
#pragma unroll
  for (int i = 0; i < FI; ++i)
#pragma unroll
    for (int j = 0; j < FJ; ++j) {
      acc[i][j][0] = 0.f; acc[i][j][1] = 0.f; acc[i][j][2] = 0.f; acc[i][j][3] = 0.f;
    }

  const int nk = ktot / 32;
  for (int kc = 0; kc < nk; ++kc) {
    const u16* Ab; int kof;
    if (kc * 32 < ksw) { Ab = A1; kof = kc * 32; }
    else               { Ab = A2; kof = kc * 32 - ksw; }
    __syncthreads();
#pragma unroll
    for (int r = 0; r < RA; ++r) {
      const int u = r * 256 + tid;
      gload_lds16(Ab + (size_t)(m0 + (u >> 2)) * lda + kof + (u & 3) * 8,
                  As + (size_t)u * 8);
    }
#pragma unroll
    for (int r = 0; r < RB; ++r) {
      const int u = r * 256 + tid;
      gload_lds16(BT + (size_t)(n0 + (u >> 2)) * ktot + kc * 32 + (u & 3) * 8,
                  Bs + (size_t)u * 8);
    }
    __syncthreads();
    bf16x8 a[FI], b[FJ];
#pragma unroll
    for (int i = 0; i < FI; ++i)
      a[i] = *(const bf16x8*)&As[(wm * FI * 16 + 16 * i + (lane & 15)) * 32 + (lane >> 4) * 8];
#pragma unroll
    for (int j = 0; j < FJ; ++j)
      b[j] = *(const bf16x8*)&Bs[(wn * FJ * 16 + 16 * j + (lane & 15)) * 32 + (lane >> 4) * 8];
#pragma unroll
    for (int i = 0; i < FI; ++i)
#pragma unroll
      for (int j = 0; j < FJ; ++j)
        acc[i][j] = __builtin_amdgcn_mfma_f32_16x16x32_bf16(a[i], b[j], acc[i][j], 0, 0, 0);
  }

  // epilogue: C/D layout col=lane&15, row=(lane>>4)*4+reg
#pragma unroll
  for (int i = 0; i < FI; ++i) {
    const int rbase = m0 + wm * FI * 16 + 16 * i + (lane >> 4) * 4;
    float deg[4];
    if (mode == 1) {
#pragma unroll
      for (int r = 0; r < 4; ++r)
        deg[r] = (float)(rp[rbase + r + 1] - rp[rbase + r]);
    }
#pragma unroll
    for (int j = 0; j < FJ; ++j) {
      const int c = n0 + wn * FJ * 16 + 16 * j + (lane & 15);
      const float bv = (c < nmax) ? bias[c] : 0.f;
#pragma unroll
      for (int r = 0; r < 4; ++r) {
        float v = acc[i][j][r];
        if (mode == 1) v += deg[r] * bv; else v += bv;
        if (mode == 2) v = fmaxf(v, 0.f);
        const size_t row = (size_t)(rbase + r);
        if (mode == 3) {
          if (c < nmax) out32[row * ldo + c] = v;
        } else {
          out16[row * ldo + c] = f2bf(v);
        }
      }
    }
  }

  // fused batch write (dec kernel only): batch[i] = i >> 4 for rows [m0, m0+BMT)
  if (mode == 3 && blockIdx.y == 0) {
    constexpr int PER = BMT * 16 / 256;
    const size_t bb = DEC_OFF + (size_t)m0 * 16;
#pragma unroll
    for (int q = 0; q < PER; ++q) {
      const int idx = tid * PER + q;
      out32[bb + idx] = (float)(m0 + (idx >> 4));
    }
  }
}

// ---------------------------------------------------------------------------
// reduce1: s1[a] = sum_e relu(zobj[obj_e] - agent_pos[a] @ W1[64:66]) (bf16 io)
// one wave per agent; 2-way unrolled gathers for MLP
// ---------------------------------------------------------------------------
__global__ __launch_bounds__(256) void k_reduce1(
    const u16* __restrict__ zobj, const float* __restrict__ agent_pos,
    const int* __restrict__ rp, const int* __restrict__ sorted_obj,
    const float* __restrict__ W1, u16* __restrict__ s1)
{
  const int a    = blockIdx.x * 4 + (threadIdx.x >> 6);
  const int lane = threadIdx.x & 63;
  const float ax = agent_pos[(size_t)a * 2 + 0];
  const float ay = agent_pos[(size_t)a * 2 + 1];
  const float4 w0 = *(const float4*)(W1 + (size_t)64 * 256 + lane * 4);
  const float4 w1 = *(const float4*)(W1 + (size_t)65 * 256 + lane * 4);
  const float t0 = ax * w0.x + ay * w1.x;
  const float t1 = ax * w0.y + ay * w1.y;
  const float t2 = ax * w0.z + ay * w1.z;
  const float t3 = ax * w0.w + ay * w1.w;
  float a0 = 0.f, a1 = 0.f, a2 = 0.f, a3 = 0.f;
  float c0 = 0.f, c1 = 0.f, c2 = 0.f, c3 = 0.f;
  const int e0 = rp[a], e1 = rp[a + 1];
  int i = e0;
  for (; i + 1 < e1; i += 2) {
    const int o1 = sorted_obj[i];
    const int o2 = sorted_obj[i + 1];
    const ushort4 z1 = *(const ushort4*)(zobj + (size_t)o1 * 256 + lane * 4);
    const ushort4 z2 = *(const ushort4*)(zobj + (size_t)o2 * 256 + lane * 4);
    a0 += fmaxf(bf2f(z1.x) - t0, 0.f);
    a1 += fmaxf(bf2f(z1.y) - t1, 0.f);
    a2 += fmaxf(bf2f(z1.z) - t2, 0.f);
    a3 += fmaxf(bf2f(z1.w) - t3, 0.f);
    c0 += fmaxf(bf2f(z2.x) - t0, 0.f);
    c1 += fmaxf(bf2f(z2.y) - t1, 0.f);
    c2 += fmaxf(bf2f(z2.z) - t2, 0.f);
    c3 += fmaxf(bf2f(z2.w) - t3, 0.f);
  }
  if (i < e1) {
    const int o = sorted_obj[i];
    const ushort4 z = *(const ushort4*)(zobj + (size_t)o * 256 + lane * 4);
    a0 += fmaxf(bf2f(z.x) - t0, 0.f);
    a1 += fmaxf(bf2f(z.y) - t1, 0.f);
    a2 += fmaxf(bf2f(z.z) - t2, 0.f);
    a3 += fmaxf(bf2f(z.w) - t3, 0.f);
  }
  a0 += c0; a1 += c1; a2 += c2; a3 += c3;
  ushort4 o4; o4.x = f2bf(a0); o4.y = f2bf(a1); o4.z = f2bf(a2); o4.w = f2bf(a3);
  *(ushort4*)(s1 + (size_t)a * 256 + lane * 4) = o4;
}

// ---------------------------------------------------------------------------
// reduce2: agg[d] = sum_e relu(y[src_e] + rel @ Wm[256:258]) (bf16 io)
// ---------------------------------------------------------------------------
__global__ __launch_bounds__(256) void k_reduce2(
    const u16* __restrict__ y, const float* __restrict__ agent_pos,
    const int* __restrict__ rp, const int* __restrict__ sorted_src,
    const float* __restrict__ Wm, u16* __restrict__ agg)
{
  const int d    = blockIdx.x * 4 + (threadIdx.x >> 6);
  const int lane = threadIdx.x & 63;
  const float dx = agent_pos[(size_t)d * 2 + 0];
  const float dy = agent_pos[(size_t)d * 2 + 1];
  const float4 w0 = *(const float4*)(Wm + (size_t)256 * 256 + lane * 4);
  const float4 w1 = *(const float4*)(Wm + (size_t)257 * 256 + lane * 4);
  float a0 = 0.f, a1 = 0.f, a2 = 0.f, a3 = 0.f;
  float c0 = 0.f, c1 = 0.f, c2 = 0.f, c3 = 0.f;
  const int e0 = rp[d], e1 = rp[d + 1];
  int i = e0;
  for (; i + 1 < e1; i += 2) {
    const int s1i = sorted_src[i];
    const int s2i = sorted_src[i + 1];
    const float rx1 = agent_pos[(size_t)s1i * 2 + 0] - dx;
    const float ry1 = agent_pos[(size_t)s1i * 2 + 1] - dy;
    const float rx2 = agent_pos[(size_t)s2i * 2 + 0] - dx;
    const float ry2 = agent_pos[(size_t)s2i * 2 + 1] - dy;
    const ushort4 v1 = *(const ushort4*)(y + (size_t)s1i * 256 + lane * 4);
    const ushort4 v2 = *(const ushort4*)(y + (size_t)s2i * 256 + lane * 4);
    a0 += fmaxf(bf2f(v1.x) + rx1 * w0.x + ry1 * w1.x, 0.f);
    a1 += fmaxf(bf2f(v1.y) + rx1 * w0.y + ry1 * w1.y, 0.f);
    a2 += fmaxf(bf2f(v1.z) + rx1 * w0.z + ry1 * w1.z, 0.f);
    a3 += fmaxf(bf2f(v1.w) + rx1 * w0.w + ry1 * w1.w, 0.f);
    c0 += fmaxf(bf2f(v2.x) + rx2 * w0.x + ry2 * w1.x, 0.f);
    c1 += fmaxf(bf2f(v2.y) + rx2 * w0.y + ry2 * w1.y, 0.f);
    c2 += fmaxf(bf2f(v2.z) + rx2 * w0.z + ry2 * w1.z, 0.f);
    c3 += fmaxf(bf2f(v2.w) + rx2 * w0.w + ry2 * w1.w, 0.f);
  }
  if (i < e1) {
    const int s = sorted_src[i];
    const float rx = agent_pos[(size_t)s * 2 + 0] - dx;
    const float ry = agent_pos[(size_t)s * 2 + 1] - dy;
    const ushort4 v = *(const ushort4*)(y + (size_t)s * 256 + lane * 4);
    a0 += fmaxf(bf2f(v.x) + rx * w0.x + ry * w1.x, 0.f);
    a1 += fmaxf(bf2f(v.y) + rx * w0.y + ry * w1.y, 0.f);
    a2 += fmaxf(bf2f(v.z) + rx * w0.z + ry * w1.z, 0.f);
    a3 += fmaxf(bf2f(v.w) + rx * w0.w + ry * w1.w, 0.f);
  }
  a0 += c0; a1 += c1; a2 += c2; a3 += c3;
  ushort4 o4; o4.x = f2bf(a0); o4.y = f2bf(a1); o4.z = f2bf(a2); o4.w = f2bf(a3);
  *(ushort4*)(agg + (size_t)d * 256 + lane * 4) = o4;
}

// ---------------------------------------------------------------------------
extern "C" void kernel_launch(void* const* d_in, const int* in_sizes, int n_in,
                              void* d_out, int out_size, void* d_ws, size_t ws_size,
                              hipStream_t stream) {
  const float* obj_x     = (const float*)d_in[0];
  const float* obj_pos   = (const float*)d_in[1];
  const float* agent_pos = (const float*)d_in[2];
  const int*   oae       = (const int*)d_in[3];
  const int*   ae        = (const int*)d_in[4];
  const float* W1 = (const float*)d_in[5];
  const float* b1 = (const float*)d_in[6];
  const float* W2 = (const float*)d_in[7];
  const float* b2 = (const float*)d_in[8];
  const float* Wm = (const float*)d_in[9];
  const float* bm = (const float*)d_in[10];
  const float* Wu = (const float*)d_in[11];
  const float* bu = (const float*)d_in[12];
  const float* Wd = (const float*)d_in[13];
  const float* bd = (const float*)d_in[14];
  float* out = (float*)d_out;

  const int* agent_idx = oae;
  const int* obj_idx   = oae + E1CNT;
  const int* src       = ae;
  const int* dst       = ae + E2CNT;

  // ---- workspace ---------------------------------------------------------
  char* p = (char*)d_ws;
  u16* slabA = (u16*)p; p += (size_t)NA * 256 * 2;      // Aobj(NOBJ*96 fits) -> s1 -> xb
  u16* slabZ = (u16*)p; p += (size_t)NOBJ * 256 * 2;    // zobj -> y | agg
  u16* enc   = (u16*)p; p += (size_t)NA * 256 * 2;
  u16* w1t = (u16*)p; p += (size_t)256 * 96 * 2;
  u16* w2t = (u16*)p; p += (size_t)256 * 256 * 2;
  u16* wmt = (u16*)p; p += (size_t)256 * 256 * 2;
  u16* wut = (u16*)p; p += (size_t)256 * 512 * 2;
  u16* wdt = (u16*)p; p += (size_t)NDECP * 256 * 2;
  int* cur1 = (int*)p;           p += (size_t)NA * 4;   // cur1|cur2 adjacent: 1 memset
  int* cur2 = (int*)p;           p += (size_t)NA * 4;
  int* rp1  = (int*)p;           p += (size_t)(NA + 1) * 4;
  int* rp2  = (int*)p;           p += (size_t)(NA + 1) * 4;
  int* sorted_obj = (int*)p;     p += (size_t)E1CNT * 4;
  int* sorted_src = (int*)p;

  u16* Aobj = slabA;
  u16* s1   = slabA;
  u16* xb   = slabA;
  u16* zobj = slabZ;
  u16* ybuf = slabZ;
  u16* agg  = slabZ + (size_t)NA * 256;

  const int BIG = 1 << 30;

  // ---- CSR (4 dispatches) ------------------------------------------------
  hipMemsetAsync(cur1, 0, (size_t)2 * NA * sizeof(int), stream);
  k_count_all<<<(E1CNT + E2CNT) / 256, 256, 0, stream>>>(agent_idx, dst, cur1, cur2);
  k_scan<<<2, 256, 0, stream>>>(cur1, rp1, cur2, rp2);
  k_fill_all<<<(E1CNT + E2CNT) / 256, 256, 0, stream>>>(
      agent_idx, obj_idx, dst, src, cur1, cur2, sorted_obj, sorted_src);

  // ---- bf16 conversions (2 dispatches) -----------------------------------
  k_prep_obj<<<NOBJ / 8, 768, 0, stream>>>(obj_x, obj_pos, Aobj);
  k_cvt_all<<<2272, 256, 0, stream>>>(W1, W2, Wm, Wu, Wd, w1t, w2t, wmt, wut, wdt);

  // ---- encode ------------------------------------------------------------
  k_mfma<128, 128, 2, 2><<<dim3(NOBJ / 128, 2), 256, 0, stream>>>(
      Aobj, Aobj, 96, w1t, 96, BIG, b1, nullptr, 0, zobj, nullptr, 256, 256);
  k_reduce1<<<NA / 4, 256, 0, stream>>>(zobj, agent_pos, rp1, sorted_obj, W1, s1);
  k_mfma<64, 128, 1, 4><<<dim3(NA / 64, 2), 256, 0, stream>>>(
      s1, s1, 256, w2t, 256, BIG, b2, rp1, 1, enc, nullptr, 256, 256);

  // ---- merge -------------------------------------------------------------
  k_mfma<64, 128, 1, 4><<<dim3(NA / 64, 2), 256, 0, stream>>>(
      enc, enc, 256, wmt, 256, BIG, bm, nullptr, 0, ybuf, nullptr, 256, 256);
  k_reduce2<<<NA / 4, 256, 0, stream>>>(ybuf, agent_pos, rp2, sorted_src, Wm, agg);
  k_mfma<64, 128, 1, 4><<<dim3(NA / 64, 2), 256, 0, stream>>>(
      enc, agg, 256, wut, 512, 256, bu, nullptr, 2, xb, nullptr, 256, 256);

  // ---- decode (+fused batch) ---------------------------------------------
  k_mfma<128, 128, 2, 2><<<dim3(NA / 128, NDECP / 128), 256, 0, stream>>>(
      xb, xb, 256, wdt, 256, BIG, bd, nullptr, 3, nullptr, out, NDEC, NDEC);
}